// Round 6
// baseline (273.999 us; speedup 1.0000x reference)
//
#include <hip/hip_runtime.h>

#define T_DATA 20000
#define S_NO   128
#define T_HIST 100
#define J_PAD  104              // conv taps padded to 13 chunks of 8 (zeros past 99)
#define NELEM  (T_DATA * S_NO)  // 2,560,000
#define NTB    1250             // 16-row time blocks

__device__ __forceinline__ float sigm(float v) {
    return 1.0f / (1.0f + __expf(-v));
}

__device__ __forceinline__ void fma4(float4& a, float s, const float4 c) {
    a.x = fmaf(s, c.x, a.x); a.y = fmaf(s, c.y, a.y);
    a.z = fmaf(s, c.z, a.z); a.w = fmaf(s, c.w, a.w);
}

__device__ __forceinline__ float anc_phi(int j, float d, float it, float K) {
    float x = fmaxf((float)j - d, 0.0f) * it;
    return K * x * __expf(-x);
}

// ---------------------------------------------------------------------------
// K1: prep (17 blocks). blocks 0..15: transpose C -> Ct[k][s]
// block 16: ancestor kernel transposed [j][s] (FIR fallback), history kernel,
// flag[0] = any(K_hist != 0), flag[1] = IIR-invalid (any delta_spike > 2),
// cof[b][q][s]: IIR taps q=0..3 -> c_0..c_3 (A[t-1..t-4]), q=4 -> c_100
// (A[t-101]), q=5 -> c_101 (A[t-102]).  Derivation: k_j satisfies
// k_j = 2r k_{j-1} - r^2 k_{j-2} (r = e^{-1/tau_b}) for j >= delta+2, so
// y_t = 2r y_{t-1} - r^2 y_{t-2} + sum(nonzero boundary taps). Exact.
// ---------------------------------------------------------------------------
__global__ void __launch_bounds__(256) k1_prep(const float* __restrict__ C,
                        const float* __restrict__ K_spike,
                        const float* __restrict__ tau_spike,
                        const float* __restrict__ delta_spike,
                        const float* __restrict__ tau_hist,
                        const float* __restrict__ K_hist,
                        const float* __restrict__ delta_hist,
                        float* __restrict__ Ct,
                        float* __restrict__ anc_kT,
                        float* __restrict__ hist_k,
                        int* __restrict__ flag,
                        float* __restrict__ cof) {
    const int tid = threadIdx.x;
    const int b   = blockIdx.x;
    if (b < 16) {
#pragma unroll
        for (int i = 0; i < 4; ++i) {
            const int q = b * 1024 + i * 256 + tid;   // q = s*128 + k
            Ct[(q & 127) * S_NO + (q >> 7)] = C[q];
        }
        return;
    }
    const int s    = tid & 127;
    const int half = tid >> 7;
    {   // ancestor kernel transposed, padded: anc_kT[j*128 + s], j in [0,104)
        float d  = delta_spike[s];
        float i0 = __expf(-tau_spike[0]);
        float i1 = __expf(-tau_spike[1]);
        float i2 = __expf(-tau_spike[2]);
        float k0 = K_spike[s * 3 + 0], k1 = K_spike[s * 3 + 1], k2 = K_spike[s * 3 + 2];
        for (int j = half * 52; j < half * 52 + 52; ++j) {
            float v = 0.0f;
            if (j < T_HIST) {
                float t  = fmaxf((float)j - d, 0.0f);
                float x0 = t * i0, x1 = t * i1, x2 = t * i2;
                v = k0 * x0 * __expf(-x0) + k1 * x1 * __expf(-x1) + k2 * x2 * __expf(-x2);
            }
            anc_kT[j * S_NO + s] = v;
        }
    }
    {   // history kernel per-subunit: hist_k[s*100 + j]
        float d  = delta_hist[s];
        float i0 = __expf(-tau_hist[0]);
        float i1 = __expf(-tau_hist[1]);
        float i2 = __expf(-tau_hist[2]);
        float k0 = K_hist[s * 3 + 0], k1 = K_hist[s * 3 + 1], k2 = K_hist[s * 3 + 2];
        for (int j = half * 50; j < half * 50 + 50; ++j) {
            float t  = fmaxf((float)j - d, 0.0f);
            float x0 = t * i0, x1 = t * i1, x2 = t * i2;
            hist_k[s * T_HIST + j] =
                k0 * x0 * __expf(-x0) + k1 * x1 * __expf(-x1) + k2 * x2 * __expf(-x2);
        }
    }
    if (tid == 0) { flag[0] = 0; flag[1] = 0; }
    __syncthreads();
    if (tid < 128) {
        if (K_hist[s * 3] != 0.0f || K_hist[s * 3 + 1] != 0.0f || K_hist[s * 3 + 2] != 0.0f)
            atomicOr(&flag[0], 1);
        const float d = delta_spike[s];
        if (d > 2.0f) atomicOr(&flag[1], 1);       // head taps would exceed 4
#pragma unroll
        for (int bb = 0; bb < 3; ++bb) {
            const float it = __expf(-tau_spike[bb]);
            const float r  = __expf(-it), r2 = r * r, tr = 2.0f * r;
            const float K  = K_spike[s * 3 + bb];
            const float p0 = anc_phi(0, d, it, K), p1 = anc_phi(1, d, it, K);
            const float p2 = anc_phi(2, d, it, K), p3 = anc_phi(3, d, it, K);
            const float p98 = anc_phi(98, d, it, K), p99 = anc_phi(99, d, it, K);
            cof[(bb * 6 + 0) * S_NO + s] = p0;
            cof[(bb * 6 + 1) * S_NO + s] = p1 - tr * p0;
            cof[(bb * 6 + 2) * S_NO + s] = p2 - tr * p1 + r2 * p0;
            cof[(bb * 6 + 3) * S_NO + s] = p3 - tr * p2 + r2 * p1;
            cof[(bb * 6 + 4) * S_NO + s] = -tr * p99 + r2 * p98;
            cof[(bb * 6 + 5) * S_NO + s] = r2 * p99;
        }
    }
}

// ---------------------------------------------------------------------------
// K2: dual GEMM  A = Z @ C^T (-> ws), R = Y @ C^T (-> out1)
// Known-good round-0 version: block 32t x 128s, thread 4t x 4s.
// ---------------------------------------------------------------------------
__global__ void __launch_bounds__(256) k2_gemm(const float* __restrict__ Z,
                                               const float* __restrict__ Y,
                                               const float* __restrict__ Ct,
                                               float* __restrict__ A,
                                               float* __restrict__ R) {
    __shared__ float Zt[32 * 128];
    __shared__ float Yt[32 * 128];
    const int t0  = blockIdx.x * 32;
    const int tid = threadIdx.x;
    {
        const float4* Zg = (const float4*)(Z + t0 * S_NO);
        const float4* Yg = (const float4*)(Y + t0 * S_NO);
        float4* Zl = (float4*)Zt;
        float4* Yl = (float4*)Yt;
        for (int q = tid; q < 1024; q += 256) { Zl[q] = Zg[q]; Yl[q] = Yg[q]; }
    }
    __syncthreads();
    const int sg = tid & 31;          // s0 = sg*4
    const int tg = tid >> 5;          // 0..7 -> local t = tg*4 + i
    const int s0 = sg * 4;
    float4 accA[4] = {{0,0,0,0},{0,0,0,0},{0,0,0,0},{0,0,0,0}};
    float4 accR[4] = {{0,0,0,0},{0,0,0,0},{0,0,0,0},{0,0,0,0}};
    for (int k4 = 0; k4 < 32; ++k4) {
        const float4 c0 = *(const float4*)&Ct[(k4 * 4 + 0) * S_NO + s0];
        const float4 c1 = *(const float4*)&Ct[(k4 * 4 + 1) * S_NO + s0];
        const float4 c2 = *(const float4*)&Ct[(k4 * 4 + 2) * S_NO + s0];
        const float4 c3 = *(const float4*)&Ct[(k4 * 4 + 3) * S_NO + s0];
#pragma unroll
        for (int i = 0; i < 4; ++i) {
            const float4 z = *(const float4*)&Zt[(tg * 4 + i) * S_NO + k4 * 4];
            fma4(accA[i], z.x, c0); fma4(accA[i], z.y, c1);
            fma4(accA[i], z.z, c2); fma4(accA[i], z.w, c3);
            const float4 y = *(const float4*)&Yt[(tg * 4 + i) * S_NO + k4 * 4];
            fma4(accR[i], y.x, c0); fma4(accR[i], y.y, c1);
            fma4(accR[i], y.z, c2); fma4(accR[i], y.w, c3);
        }
    }
#pragma unroll
    for (int i = 0; i < 4; ++i) {
        *(float4*)&A[(t0 + tg * 4 + i) * S_NO + s0] = accA[i];
        *(float4*)&R[(t0 + tg * 4 + i) * S_NO + s0] = accR[i];
    }
}

// ---------------------------------------------------------------------------
// K3a: IIR zero-state pass. Thread = (s, 16-row t-block). Computes per-basis
// y_zs via the 2nd-order recurrence (zero initial state), writes partial
// filtered sum -> Fws and per-block end states -> Ezs. ~384 FMA + 36 loads
// per thread vs the FIR's ~1664 FMA + 430 loads per 16 outputs.
// ---------------------------------------------------------------------------
__global__ void __launch_bounds__(256) k3a_iir(const float* __restrict__ A,
                                               const float* __restrict__ tau_spike,
                                               const float* __restrict__ cof,
                                               const int* __restrict__ flag,
                                               float* __restrict__ Fws,
                                               float* __restrict__ Ezs) {
    if (flag[1]) return;
    const int tid = threadIdx.x;
    const int s   = tid & 127;
    const int sub = tid >> 7;
    const int tb  = blockIdx.x * 2 + sub;
    const int T0  = tb * 16;

    float tr[3], nr2[3];
#pragma unroll
    for (int b = 0; b < 3; ++b) {
        float it = __expf(-tau_spike[b]);
        float r  = __expf(-it);
        tr[b] = 2.0f * r; nr2[b] = -r * r;
    }
    float cf[3][6];
#pragma unroll
    for (int b = 0; b < 3; ++b)
#pragma unroll
        for (int q = 0; q < 6; ++q) cf[b][q] = cof[(b * 6 + q) * S_NO + s];

    // windows: head rows [T0-4, T0+14] (19), tail rows [T0-102, T0-86] (17)
    float hw[19], tl[17];
    if (tb >= 7) {
#pragma unroll
        for (int q = 0; q < 19; ++q) hw[q] = A[(T0 - 4 + q) * S_NO + s];
#pragma unroll
        for (int q = 0; q < 17; ++q) tl[q] = A[(T0 - 102 + q) * S_NO + s];
    } else {
#pragma unroll
        for (int q = 0; q < 19; ++q) {
            const int u = T0 - 4 + q;
            hw[q] = (u >= 0) ? A[u * S_NO + s] : 0.0f;
        }
#pragma unroll
        for (int q = 0; q < 17; ++q) {
            const int u = T0 - 102 + q;
            tl[q] = (u >= 0) ? A[u * S_NO + s] : 0.0f;
        }
    }

    float y1[3] = {0,0,0}, y2[3] = {0,0,0};
#pragma unroll
    for (int i = 0; i < 16; ++i) {
        float fs = 0.0f;
#pragma unroll
        for (int b = 0; b < 3; ++b) {
            float u = cf[b][0] * hw[i + 3];
            u = fmaf(cf[b][1], hw[i + 2], u);
            u = fmaf(cf[b][2], hw[i + 1], u);
            u = fmaf(cf[b][3], hw[i],     u);
            u = fmaf(cf[b][4], tl[i + 1], u);
            u = fmaf(cf[b][5], tl[i],     u);
            float y = fmaf(tr[b], y1[b], u);
            y = fmaf(nr2[b], y2[b], y);
            y2[b] = y1[b]; y1[b] = y;
            fs += y;
        }
        Fws[(T0 + i) * S_NO + s] = fs;
    }
    float2* E = (float2*)Ezs;
#pragma unroll
    for (int b = 0; b < 3; ++b)
        E[(tb * 3 + b) * S_NO + s] = make_float2(y1[b], y2[b]);
}

// ---------------------------------------------------------------------------
// K3b: sequential 2x2 state scan over the 1250 t-blocks. 384 independent
// scans (s x basis). state_in(tb) stored to Sin; state advances by
// M^16 * state + Ezs(tb) (M = [[2r,-r^2],[1,0]], M^16 by 4 squarings).
// ---------------------------------------------------------------------------
__global__ void __launch_bounds__(384) k3b_scan(const float* __restrict__ tau_spike,
                                                const int* __restrict__ flag,
                                                const float* __restrict__ Ezs,
                                                float* __restrict__ Sin) {
    if (flag[1]) return;
    const int tid = threadIdx.x;
    const int s   = tid & 127;
    const int b   = tid >> 7;           // 0..2
    const float it = __expf(-tau_spike[b]);
    const float r  = __expf(-it);
    float m00 = 2.0f * r, m01 = -r * r, m10 = 1.0f, m11 = 0.0f;
#pragma unroll
    for (int k = 0; k < 4; ++k) {       // -> M^16
        float a00 = m00 * m00 + m01 * m10, a01 = m00 * m01 + m01 * m11;
        float a10 = m10 * m00 + m11 * m10, a11 = m10 * m01 + m11 * m11;
        m00 = a00; m01 = a01; m10 = a10; m11 = a11;
    }
    const float2* E = (const float2*)Ezs;
    float2* S = (float2*)Sin;
    float y1 = 0.0f, y2 = 0.0f;
    for (int tb = 0; tb < NTB; ++tb) {
        const int idx = (tb * 3 + b) * S_NO + s;
        S[idx] = make_float2(y1, y2);
        const float2 e = E[idx];
        const float n1 = m00 * y1 + m01 * y2 + e.x;
        const float n2 = m10 * y1 + m11 * y2 + e.y;
        y1 = n1; y2 = n2;
    }
}

// ---------------------------------------------------------------------------
// K3c: correction + final map (streaming). filtered[t] = Fws[t] +
// sum_b row0(M_b^{dt+1}) . Sin_b  (dt = t - 16*blk). Row iterated by
// (a,b) -> (2r a + b, -r^2 a). Fallback flag[1]: full FIR (proven R5
// rolling-window path) from A.
// ---------------------------------------------------------------------------
#define K3_LOGICAL 1250
#define K3_NPER    157                 // ceil(1250/8)
#define K3_PHYS    (8 * K3_NPER)       // 1256

__device__ __forceinline__ void k3_fma_chunk(const float w[15], const float kj[8],
                                             float acc[8]) {
#pragma unroll
    for (int r = 0; r < 8; ++r)
#pragma unroll
        for (int i = 0; i < 8; ++i)
            acc[i] = fmaf(kj[r], w[i + 7 - r], acc[i]);   // row = t0+i-1-(8c+r)
}

__device__ __forceinline__ void conv8_guard(const float* __restrict__ A,
                                            const float* __restrict__ kT,
                                            int t0, int s, float acc[8]) {
#pragma unroll 1
    for (int c = 0; c < 13; ++c) {
        const int B = t0 - 8 * c - 8;
        float w[15], kj[8];
#pragma unroll
        for (int q = 0; q < 15; ++q) {
            const int u = B + q;
            w[q] = (u >= 0) ? A[u * S_NO + s] : 0.0f;
        }
#pragma unroll
        for (int r = 0; r < 8; ++r) kj[r] = kT[(8 * c + r) * S_NO + s];
        k3_fma_chunk(w, kj, acc);
    }
}

__global__ void __launch_bounds__(256, 4) k3c_final(const float* __restrict__ A,
                                                const float* __restrict__ anc_kT,
                                                const float* __restrict__ tau_spike,
                                                const float* __restrict__ Sin,
                                                const float* __restrict__ S_conv,
                                                const float* __restrict__ noise,
                                                const float* __restrict__ W_sub,
                                                const float* __restrict__ theta_syn,
                                                const float* __restrict__ theta_spike,
                                                const float* __restrict__ W_spike,
                                                const int* __restrict__ flag,
                                                float* __restrict__ out0,
                                                float* __restrict__ out1,
                                                float* __restrict__ out2,
                                                float* __restrict__ out3,
                                                float* __restrict__ Fws) {
    // bijective XCD swizzle over the padded grid [0, 1256)
    const int blk = (blockIdx.x & 7) * K3_NPER + (blockIdx.x >> 3);
    if (blk >= K3_LOGICAL) return;
    const int tid  = threadIdx.x;
    const int s    = tid & 127;
    const int tg   = tid >> 7;                            // wave-uniform (0/1)
    const int t0   = blk * 16 + tg * 8;
    const int fl   = flag[0];
    const int mode = flag[1];

    // prefetch the HBM streams; latency hides under correction math
    float sc[8], nz[8], rr[8];
#pragma unroll
    for (int i = 0; i < 8; ++i) {
        const int n = (t0 + i) * S_NO + s;
        sc[i] = S_conv[n];
        nz[i] = noise[n];
        rr[i] = out1[n];              // R = Y @ C^T, written by K2
    }

    float filt[8];
    if (mode == 0) {
        float tr[3], nr2[3];
#pragma unroll
        for (int b = 0; b < 3; ++b) {
            float it = __expf(-tau_spike[b]);
            float r  = __expf(-it);
            tr[b] = 2.0f * r; nr2[b] = -r * r;
        }
        float pa[3], pb[3];                               // row0 of M^{dt+1}
#pragma unroll
        for (int b = 0; b < 3; ++b) { pa[b] = tr[b]; pb[b] = nr2[b]; }
        if (tg) {
#pragma unroll
            for (int k = 0; k < 8; ++k)
#pragma unroll
                for (int b = 0; b < 3; ++b) {
                    const float na = fmaf(tr[b], pa[b], pb[b]);
                    pb[b] = nr2[b] * pa[b]; pa[b] = na;
                }
        }
        float2 si[3];
        const float2* S2 = (const float2*)Sin;
#pragma unroll
        for (int b = 0; b < 3; ++b) si[b] = S2[(blk * 3 + b) * S_NO + s];
#pragma unroll
        for (int i = 0; i < 8; ++i) {
            float c = 0.0f;
#pragma unroll
            for (int b = 0; b < 3; ++b) {
                c = fmaf(pa[b], si[b].x, c);
                c = fmaf(pb[b], si[b].y, c);
                const float na = fmaf(tr[b], pa[b], pb[b]);
                pb[b] = nr2[b] * pa[b]; pa[b] = na;
            }
            filt[i] = Fws[(t0 + i) * S_NO + s] + c;
        }
    } else {
        // fallback: full 100-tap FIR (R5 rolling-window, proven)
        float acc[8] = {0,0,0,0,0,0,0,0};
        if (t0 >= J_PAD) {
            float w[15], kj[8];
            {
                const int B = t0 - 8;
#pragma unroll
                for (int q = 0; q < 15; ++q) w[q] = A[(B + q) * S_NO + s];
#pragma unroll
                for (int r = 0; r < 8; ++r) kj[r] = anc_kT[r * S_NO + s];
                k3_fma_chunk(w, kj, acc);
            }
#pragma unroll
            for (int c = 1; c < 13; ++c) {
                const int B = t0 - 8 * c - 8;
#pragma unroll
                for (int q = 6; q >= 0; --q) w[q + 8] = w[q];
#pragma unroll
                for (int q = 0; q < 8; ++q) w[q] = A[(B + q) * S_NO + s];
#pragma unroll
                for (int r = 0; r < 8; ++r) kj[r] = anc_kT[(8 * c + r) * S_NO + s];
                k3_fma_chunk(w, kj, acc);
            }
        } else {
            conv8_guard(A, anc_kT, t0, s, acc);
        }
#pragma unroll
        for (int i = 0; i < 8; ++i) filt[i] = acc[i];
    }

    if (fl == 0) {
        const float tsy = theta_syn[s], wsub = W_sub[s];
        const float wsp = W_spike[s],  tsp  = theta_spike[s];
#pragma unroll
        for (int i = 0; i < 8; ++i) {
            const int n = (t0 + i) * S_NO + s;
            const float x  = sigm(sc[i] + tsy + rr[i] + filt[i]);
            const float dn = fmaf(x, wsp, tsp);
            const float z  = sigm(dn + nz[i]);
            out0[n] = x * wsub;
            out1[n] = z;
            out2[n] = dn;
            out3[n] = dn;
        }
    } else {
#pragma unroll
        for (int i = 0; i < 8; ++i) Fws[(t0 + i) * S_NO + s] = filt[i];
    }
}

// ---------------------------------------------------------------------------
// K4: exact sequential recurrence (only when hist kernel != 0).
// ---------------------------------------------------------------------------
__global__ void __launch_bounds__(64) k4_scan(const float* __restrict__ S_conv,
                                              const float* __restrict__ noise,
                                              const float* __restrict__ W_sub,
                                              const float* __restrict__ theta_syn,
                                              const float* __restrict__ theta_spike,
                                              const float* __restrict__ W_spike,
                                              const float* __restrict__ hist_k,
                                              const int* __restrict__ flag,
                                              const float* __restrict__ Fws,
                                              float* __restrict__ out0,
                                              float* __restrict__ out1,
                                              float* __restrict__ out2,
                                              float* __restrict__ out3) {
    if (flag[0] == 0) return;
    __shared__ float zr[128];
    const int s = blockIdx.x;
    const int l = threadIdx.x;
    zr[l] = 0.0f; zr[l + 64] = 0.0f;      // single wave: no barrier needed
    const float hk0 = (l < T_HIST) ? hist_k[s * T_HIST + l] : 0.0f;
    const float hk1 = (l + 64 < T_HIST) ? hist_k[s * T_HIST + l + 64] : 0.0f;
    const float tsy = theta_syn[s], wsub = W_sub[s];
    const float wsp = W_spike[s],  tsp  = theta_spike[s];
    for (int t = 0; t < T_DATA; ++t) {
        float fh = hk0 * zr[(t - 1 - l) & 127];
        fh = fmaf(hk1, zr[(t - 65 - l) & 127], fh);
#pragma unroll
        for (int m = 1; m < 64; m <<= 1) fh += __shfl_xor(fh, m, 64);
        const int n = t * S_NO + s;
        const float basev = S_conv[n] + tsy + out1[n] + Fws[n];
        const float x  = sigm(basev + fh);
        const float dn = fmaf(x, wsp, tsp);
        const float z  = sigm(dn + noise[n]);
        if (l == 0) {
            out0[n] = x * wsub;
            out1[n] = z;
            out2[n] = dn;
            out3[n] = dn;
            zr[t & 127] = z;
        }
    }
}

// ---------------------------------------------------------------------------
extern "C" void kernel_launch(void* const* d_in, const int* in_sizes, int n_in,
                              void* d_out, int out_size, void* d_ws, size_t ws_size,
                              hipStream_t stream) {
    const float* S_conv  = (const float*)d_in[0];
    const float* Y_anc   = (const float*)d_in[1];
    const float* Z_anc   = (const float*)d_in[2];
    const float* noise   = (const float*)d_in[3];
    const float* C_den   = (const float*)d_in[4];
    const float* W_sub   = (const float*)d_in[5];
    const float* th_syn  = (const float*)d_in[6];
    const float* K_spk   = (const float*)d_in[7];
    const float* tau_spk = (const float*)d_in[8];
    const float* dl_spk  = (const float*)d_in[9];
    const float* th_spk  = (const float*)d_in[10];
    const float* W_spk   = (const float*)d_in[11];
    const float* tau_h   = (const float*)d_in[12];
    const float* K_h     = (const float*)d_in[13];
    const float* dl_h    = (const float*)d_in[14];

    float* out  = (float*)d_out;
    float* out0 = out;
    float* out1 = out + NELEM;
    float* out2 = out + 2 * NELEM;
    float* out3 = out + 3 * NELEM;

    // workspace: A | F | Ct | anc_kT | hist_k | flag[4] | cof | Ezs | Sin
    float* ws     = (float*)d_ws;
    float* wsA    = ws;
    float* wsF    = ws + NELEM;
    float* Ct     = ws + 2 * NELEM;
    float* anc_kT = Ct + S_NO * S_NO;
    float* hist_k = anc_kT + J_PAD * S_NO;
    int*   flag   = (int*)(hist_k + S_NO * T_HIST);
    float* cof    = (float*)(flag + 4);
    float* Ezs    = cof + 18 * S_NO;
    float* Sin    = Ezs + NTB * 3 * S_NO * 2;

    k1_prep<<<17, 256, 0, stream>>>(C_den, K_spk, tau_spk, dl_spk, tau_h, K_h, dl_h,
                                    Ct, anc_kT, hist_k, flag, cof);
    // A -> ws, R -> out1
    k2_gemm<<<T_DATA / 32, 256, 0, stream>>>(Z_anc, Y_anc, Ct, wsA, out1);
    // IIR conv: zero-state pass -> state scan -> correction + final map
    k3a_iir<<<NTB / 2, 256, 0, stream>>>(wsA, tau_spk, cof, flag, wsF, Ezs);
    k3b_scan<<<1, 384, 0, stream>>>(tau_spk, flag, Ezs, Sin);
    k3c_final<<<K3_PHYS, 256, 0, stream>>>(wsA, anc_kT, tau_spk, Sin,
                                           S_conv, noise, W_sub, th_syn, th_spk,
                                           W_spk, flag, out0, out1, out2, out3, wsF);
    // exact sequential path (no-op when hist kernel is all-zero)
    k4_scan<<<S_NO, 64, 0, stream>>>(S_conv, noise, W_sub, th_syn, th_spk, W_spk,
                                     hist_k, flag, wsF, out0, out1, out2, out3);
}

// Round 7
// 176.990 us; speedup vs baseline: 1.5481x; 1.5481x over previous
//
#include <hip/hip_runtime.h>

#define T_DATA 20000
#define S_NO   128
#define T_HIST 100
#define J_PAD  104              // conv taps padded to 13 chunks of 8 (zeros past 99)
#define NELEM  (T_DATA * S_NO)  // 2,560,000
#define NTB    1250             // 16-row time blocks

__device__ __forceinline__ float sigm(float v) {
    return 1.0f / (1.0f + __expf(-v));
}

__device__ __forceinline__ void fma4(float4& a, float s, const float4 c) {
    a.x = fmaf(s, c.x, a.x); a.y = fmaf(s, c.y, a.y);
    a.z = fmaf(s, c.z, a.z); a.w = fmaf(s, c.w, a.w);
}

__device__ __forceinline__ float anc_phi(int j, float d, float it, float K) {
    float x = fmaxf((float)j - d, 0.0f) * it;
    return K * x * __expf(-x);
}

struct M2 { float a, b, c, d; };
__device__ __forceinline__ M2 mmul(M2 x, M2 y) {      // x*y
    M2 r;
    r.a = fmaf(x.a, y.a, x.b * y.c); r.b = fmaf(x.a, y.b, x.b * y.d);
    r.c = fmaf(x.c, y.a, x.d * y.c); r.d = fmaf(x.c, y.b, x.d * y.d);
    return r;
}

// ---------------------------------------------------------------------------
// K1: prep (17 blocks). blocks 0..15: transpose C -> Ct[k][s]
// block 16: ancestor kernel transposed [j][s] (FIR fallback), history kernel,
// flag[0] = any(K_hist != 0), flag[1] = IIR-invalid (any delta_spike > 2),
// cof[b][q][s]: IIR taps q=0..3 -> c_0..c_3 (A[t-1..t-4]), q=4 -> c_100
// (A[t-101]), q=5 -> c_101 (A[t-102]).  k_j = 2r k_{j-1} - r^2 k_{j-2}
// (r = e^{-1/tau_b}) for j >= delta+2 -> exact 2nd-order IIR + boundary taps.
// ---------------------------------------------------------------------------
__global__ void __launch_bounds__(256) k1_prep(const float* __restrict__ C,
                        const float* __restrict__ K_spike,
                        const float* __restrict__ tau_spike,
                        const float* __restrict__ delta_spike,
                        const float* __restrict__ tau_hist,
                        const float* __restrict__ K_hist,
                        const float* __restrict__ delta_hist,
                        float* __restrict__ Ct,
                        float* __restrict__ anc_kT,
                        float* __restrict__ hist_k,
                        int* __restrict__ flag,
                        float* __restrict__ cof) {
    const int tid = threadIdx.x;
    const int b   = blockIdx.x;
    if (b < 16) {
#pragma unroll
        for (int i = 0; i < 4; ++i) {
            const int q = b * 1024 + i * 256 + tid;   // q = s*128 + k
            Ct[(q & 127) * S_NO + (q >> 7)] = C[q];
        }
        return;
    }
    const int s    = tid & 127;
    const int half = tid >> 7;
    {   // ancestor kernel transposed, padded: anc_kT[j*128 + s], j in [0,104)
        float d  = delta_spike[s];
        float i0 = __expf(-tau_spike[0]);
        float i1 = __expf(-tau_spike[1]);
        float i2 = __expf(-tau_spike[2]);
        float k0 = K_spike[s * 3 + 0], k1 = K_spike[s * 3 + 1], k2 = K_spike[s * 3 + 2];
        for (int j = half * 52; j < half * 52 + 52; ++j) {
            float v = 0.0f;
            if (j < T_HIST) {
                float t  = fmaxf((float)j - d, 0.0f);
                float x0 = t * i0, x1 = t * i1, x2 = t * i2;
                v = k0 * x0 * __expf(-x0) + k1 * x1 * __expf(-x1) + k2 * x2 * __expf(-x2);
            }
            anc_kT[j * S_NO + s] = v;
        }
    }
    {   // history kernel per-subunit: hist_k[s*100 + j]
        float d  = delta_hist[s];
        float i0 = __expf(-tau_hist[0]);
        float i1 = __expf(-tau_hist[1]);
        float i2 = __expf(-tau_hist[2]);
        float k0 = K_hist[s * 3 + 0], k1 = K_hist[s * 3 + 1], k2 = K_hist[s * 3 + 2];
        for (int j = half * 50; j < half * 50 + 50; ++j) {
            float t  = fmaxf((float)j - d, 0.0f);
            float x0 = t * i0, x1 = t * i1, x2 = t * i2;
            hist_k[s * T_HIST + j] =
                k0 * x0 * __expf(-x0) + k1 * x1 * __expf(-x1) + k2 * x2 * __expf(-x2);
        }
    }
    if (tid == 0) { flag[0] = 0; flag[1] = 0; }
    __syncthreads();
    if (tid < 128) {
        if (K_hist[s * 3] != 0.0f || K_hist[s * 3 + 1] != 0.0f || K_hist[s * 3 + 2] != 0.0f)
            atomicOr(&flag[0], 1);
        const float d = delta_spike[s];
        if (d > 2.0f) atomicOr(&flag[1], 1);       // head taps would exceed 4
#pragma unroll
        for (int bb = 0; bb < 3; ++bb) {
            const float it = __expf(-tau_spike[bb]);
            const float r  = __expf(-it), r2 = r * r, tr = 2.0f * r;
            const float K  = K_spike[s * 3 + bb];
            const float p0 = anc_phi(0, d, it, K), p1 = anc_phi(1, d, it, K);
            const float p2 = anc_phi(2, d, it, K), p3 = anc_phi(3, d, it, K);
            const float p98 = anc_phi(98, d, it, K), p99 = anc_phi(99, d, it, K);
            cof[(bb * 6 + 0) * S_NO + s] = p0;
            cof[(bb * 6 + 1) * S_NO + s] = p1 - tr * p0;
            cof[(bb * 6 + 2) * S_NO + s] = p2 - tr * p1 + r2 * p0;
            cof[(bb * 6 + 3) * S_NO + s] = p3 - tr * p2 + r2 * p1;
            cof[(bb * 6 + 4) * S_NO + s] = -tr * p99 + r2 * p98;
            cof[(bb * 6 + 5) * S_NO + s] = r2 * p99;
        }
    }
}

// ---------------------------------------------------------------------------
// K2: dual GEMM  A = Z @ C^T (-> ws), R = Y @ C^T (-> out1)
// Known-good round-0 version: block 32t x 128s, thread 4t x 4s.
// ---------------------------------------------------------------------------
__global__ void __launch_bounds__(256) k2_gemm(const float* __restrict__ Z,
                                               const float* __restrict__ Y,
                                               const float* __restrict__ Ct,
                                               float* __restrict__ A,
                                               float* __restrict__ R) {
    __shared__ float Zt[32 * 128];
    __shared__ float Yt[32 * 128];
    const int t0  = blockIdx.x * 32;
    const int tid = threadIdx.x;
    {
        const float4* Zg = (const float4*)(Z + t0 * S_NO);
        const float4* Yg = (const float4*)(Y + t0 * S_NO);
        float4* Zl = (float4*)Zt;
        float4* Yl = (float4*)Yt;
        for (int q = tid; q < 1024; q += 256) { Zl[q] = Zg[q]; Yl[q] = Yg[q]; }
    }
    __syncthreads();
    const int sg = tid & 31;          // s0 = sg*4
    const int tg = tid >> 5;          // 0..7 -> local t = tg*4 + i
    const int s0 = sg * 4;
    float4 accA[4] = {{0,0,0,0},{0,0,0,0},{0,0,0,0},{0,0,0,0}};
    float4 accR[4] = {{0,0,0,0},{0,0,0,0},{0,0,0,0},{0,0,0,0}};
    for (int k4 = 0; k4 < 32; ++k4) {
        const float4 c0 = *(const float4*)&Ct[(k4 * 4 + 0) * S_NO + s0];
        const float4 c1 = *(const float4*)&Ct[(k4 * 4 + 1) * S_NO + s0];
        const float4 c2 = *(const float4*)&Ct[(k4 * 4 + 2) * S_NO + s0];
        const float4 c3 = *(const float4*)&Ct[(k4 * 4 + 3) * S_NO + s0];
#pragma unroll
        for (int i = 0; i < 4; ++i) {
            const float4 z = *(const float4*)&Zt[(tg * 4 + i) * S_NO + k4 * 4];
            fma4(accA[i], z.x, c0); fma4(accA[i], z.y, c1);
            fma4(accA[i], z.z, c2); fma4(accA[i], z.w, c3);
            const float4 y = *(const float4*)&Yt[(tg * 4 + i) * S_NO + k4 * 4];
            fma4(accR[i], y.x, c0); fma4(accR[i], y.y, c1);
            fma4(accR[i], y.z, c2); fma4(accR[i], y.w, c3);
        }
    }
#pragma unroll
    for (int i = 0; i < 4; ++i) {
        *(float4*)&A[(t0 + tg * 4 + i) * S_NO + s0] = accA[i];
        *(float4*)&R[(t0 + tg * 4 + i) * S_NO + s0] = accR[i];
    }
}

// ---------------------------------------------------------------------------
// K3a: IIR zero-state pass. Thread = (s, 16-row t-block). Computes per-basis
// y_zs via the 2nd-order recurrence (zero initial state), writes partial
// filtered sum -> Fws and per-block end states -> Ezs.
// ---------------------------------------------------------------------------
__global__ void __launch_bounds__(256) k3a_iir(const float* __restrict__ A,
                                               const float* __restrict__ tau_spike,
                                               const float* __restrict__ cof,
                                               const int* __restrict__ flag,
                                               float* __restrict__ Fws,
                                               float* __restrict__ Ezs) {
    if (flag[1]) return;
    const int tid = threadIdx.x;
    const int s   = tid & 127;
    const int sub = tid >> 7;
    const int tb  = blockIdx.x * 2 + sub;
    const int T0  = tb * 16;

    float tr[3], nr2[3];
#pragma unroll
    for (int b = 0; b < 3; ++b) {
        float it = __expf(-tau_spike[b]);
        float r  = __expf(-it);
        tr[b] = 2.0f * r; nr2[b] = -r * r;
    }
    float cf[3][6];
#pragma unroll
    for (int b = 0; b < 3; ++b)
#pragma unroll
        for (int q = 0; q < 6; ++q) cf[b][q] = cof[(b * 6 + q) * S_NO + s];

    // windows: head rows [T0-4, T0+14] (19), tail rows [T0-102, T0-86] (17)
    float hw[19], tl[17];
    if (tb >= 7) {
#pragma unroll
        for (int q = 0; q < 19; ++q) hw[q] = A[(T0 - 4 + q) * S_NO + s];
#pragma unroll
        for (int q = 0; q < 17; ++q) tl[q] = A[(T0 - 102 + q) * S_NO + s];
    } else {
#pragma unroll
        for (int q = 0; q < 19; ++q) {
            const int u = T0 - 4 + q;
            hw[q] = (u >= 0) ? A[u * S_NO + s] : 0.0f;
        }
#pragma unroll
        for (int q = 0; q < 17; ++q) {
            const int u = T0 - 102 + q;
            tl[q] = (u >= 0) ? A[u * S_NO + s] : 0.0f;
        }
    }

    float y1[3] = {0,0,0}, y2[3] = {0,0,0};
#pragma unroll
    for (int i = 0; i < 16; ++i) {
        float fs = 0.0f;
#pragma unroll
        for (int b = 0; b < 3; ++b) {
            float u = cf[b][0] * hw[i + 3];
            u = fmaf(cf[b][1], hw[i + 2], u);
            u = fmaf(cf[b][2], hw[i + 1], u);
            u = fmaf(cf[b][3], hw[i],     u);
            u = fmaf(cf[b][4], tl[i + 1], u);
            u = fmaf(cf[b][5], tl[i],     u);
            float y = fmaf(tr[b], y1[b], u);
            y = fmaf(nr2[b], y2[b], y);
            y2[b] = y1[b]; y1[b] = y;
            fs += y;
        }
        Fws[(T0 + i) * S_NO + s] = fs;
    }
    float2* E = (float2*)Ezs;
#pragma unroll
    for (int b = 0; b < 3; ++b)
        E[(tb * 3 + b) * S_NO + s] = make_float2(y1[b], y2[b]);
}

// ---------------------------------------------------------------------------
// K3b: PARALLEL weighted prefix scan over the 1250 t-blocks.
// One wave per (s, basis) scan: 384 blocks x 64 lanes. Lane owns a 20-block
// segment: forward-recur segment summary (zero state), Kogge-Stone inclusive
// scan across lanes with matrix weights P^o (P = M16^20, by squaring),
// exclusive shift, replay segment writing incoming states -> Sin.
// Serial depth: 1250 -> 20 + 6 shuffle steps (was 112 us, single block).
// ---------------------------------------------------------------------------
__global__ void __launch_bounds__(64) k3b_scan(const float* __restrict__ tau_spike,
                                               const int* __restrict__ flag,
                                               const float* __restrict__ Ezs,
                                               float* __restrict__ Sin) {
    if (flag[1]) return;
    const int l = threadIdx.x;          // 0..63
    const int s = blockIdx.x & 127;
    const int b = blockIdx.x >> 7;      // 0..2
    const float it = __expf(-tau_spike[b]);
    const float r  = __expf(-it);
    M2 M = {2.0f * r, -r * r, 1.0f, 0.0f};
    M2 M16 = mmul(M, M); M16 = mmul(M16, M16);
    M16 = mmul(M16, M16); M16 = mmul(M16, M16);        // M^16
    M2 q2 = mmul(M16, M16), q4 = mmul(q2, q2);
    M2 q8 = mmul(q4, q4),   q16 = mmul(q8, q8);
    M2 P  = mmul(q16, q4);                             // M16^20

    const float2* E = (const float2*)Ezs;
    float2* S = (float2*)Sin;
    const int j0 = l * 20;
    float2 e[20];
#pragma unroll
    for (int i = 0; i < 20; ++i) {
        const int j = j0 + i;
        e[i] = (j < NTB) ? E[(j * 3 + b) * S_NO + s] : make_float2(0.0f, 0.0f);
    }
    // segment summary: v = sum_i M16^(19-i) e_i (forward recurrence, zero state)
    float v1 = 0.0f, v2 = 0.0f;
#pragma unroll
    for (int i = 0; i < 20; ++i) {
        const float n1 = fmaf(M16.a, v1, fmaf(M16.b, v2, e[i].x));
        const float n2 = fmaf(M16.c, v1, fmaf(M16.d, v2, e[i].y));
        v1 = n1; v2 = n2;
    }
    // Kogge-Stone inclusive scan: S_l = sum_{m<=l} P^(l-m) v_m
    M2 pw = P;
    float S1 = v1, S2 = v2;
#pragma unroll
    for (int o = 1; o < 64; o <<= 1) {
        const float a1 = __shfl_up(S1, o, 64);
        const float a2 = __shfl_up(S2, o, 64);
        if (l >= o) {
            S1 = fmaf(pw.a, a1, fmaf(pw.b, a2, S1));
            S2 = fmaf(pw.c, a1, fmaf(pw.d, a2, S2));
        }
        pw = mmul(pw, pw);
    }
    // exclusive: incoming state of lane l's segment
    float u1 = __shfl_up(S1, 1, 64), u2 = __shfl_up(S2, 1, 64);
    if (l == 0) { u1 = 0.0f; u2 = 0.0f; }
    // replay: write incoming state per t-block
#pragma unroll
    for (int i = 0; i < 20; ++i) {
        const int j = j0 + i;
        if (j < NTB) S[(j * 3 + b) * S_NO + s] = make_float2(u1, u2);
        const float n1 = fmaf(M16.a, u1, fmaf(M16.b, u2, e[i].x));
        const float n2 = fmaf(M16.c, u1, fmaf(M16.d, u2, e[i].y));
        u1 = n1; u2 = n2;
    }
}

// ---------------------------------------------------------------------------
// K3c: correction + final map (streaming). filtered[t] = Fws[t] +
// sum_b row0(M_b^{dt+1}) . Sin_b  (dt = t - 16*blk). Fallback flag[1]:
// full FIR (proven R5 rolling-window path) from A.
// ---------------------------------------------------------------------------
#define K3_LOGICAL 1250
#define K3_NPER    157                 // ceil(1250/8)
#define K3_PHYS    (8 * K3_NPER)       // 1256

__device__ __forceinline__ void k3_fma_chunk(const float w[15], const float kj[8],
                                             float acc[8]) {
#pragma unroll
    for (int r = 0; r < 8; ++r)
#pragma unroll
        for (int i = 0; i < 8; ++i)
            acc[i] = fmaf(kj[r], w[i + 7 - r], acc[i]);   // row = t0+i-1-(8c+r)
}

__device__ __forceinline__ void conv8_guard(const float* __restrict__ A,
                                            const float* __restrict__ kT,
                                            int t0, int s, float acc[8]) {
#pragma unroll 1
    for (int c = 0; c < 13; ++c) {
        const int B = t0 - 8 * c - 8;
        float w[15], kj[8];
#pragma unroll
        for (int q = 0; q < 15; ++q) {
            const int u = B + q;
            w[q] = (u >= 0) ? A[u * S_NO + s] : 0.0f;
        }
#pragma unroll
        for (int r = 0; r < 8; ++r) kj[r] = kT[(8 * c + r) * S_NO + s];
        k3_fma_chunk(w, kj, acc);
    }
}

__global__ void __launch_bounds__(256, 4) k3c_final(const float* __restrict__ A,
                                                const float* __restrict__ anc_kT,
                                                const float* __restrict__ tau_spike,
                                                const float* __restrict__ Sin,
                                                const float* __restrict__ S_conv,
                                                const float* __restrict__ noise,
                                                const float* __restrict__ W_sub,
                                                const float* __restrict__ theta_syn,
                                                const float* __restrict__ theta_spike,
                                                const float* __restrict__ W_spike,
                                                const int* __restrict__ flag,
                                                float* __restrict__ out0,
                                                float* __restrict__ out1,
                                                float* __restrict__ out2,
                                                float* __restrict__ out3,
                                                float* __restrict__ Fws) {
    // bijective XCD swizzle over the padded grid [0, 1256)
    const int blk = (blockIdx.x & 7) * K3_NPER + (blockIdx.x >> 3);
    if (blk >= K3_LOGICAL) return;
    const int tid  = threadIdx.x;
    const int s    = tid & 127;
    const int tg   = tid >> 7;                            // wave-uniform (0/1)
    const int t0   = blk * 16 + tg * 8;
    const int fl   = flag[0];
    const int mode = flag[1];

    // prefetch the HBM streams; latency hides under correction math
    float sc[8], nz[8], rr[8];
#pragma unroll
    for (int i = 0; i < 8; ++i) {
        const int n = (t0 + i) * S_NO + s;
        sc[i] = S_conv[n];
        nz[i] = noise[n];
        rr[i] = out1[n];              // R = Y @ C^T, written by K2
    }

    float filt[8];
    if (mode == 0) {
        float tr[3], nr2[3];
#pragma unroll
        for (int b = 0; b < 3; ++b) {
            float it = __expf(-tau_spike[b]);
            float r  = __expf(-it);
            tr[b] = 2.0f * r; nr2[b] = -r * r;
        }
        float pa[3], pb[3];                               // row0 of M^{dt+1}
#pragma unroll
        for (int b = 0; b < 3; ++b) { pa[b] = tr[b]; pb[b] = nr2[b]; }
        if (tg) {
#pragma unroll
            for (int k = 0; k < 8; ++k)
#pragma unroll
                for (int b = 0; b < 3; ++b) {
                    const float na = fmaf(tr[b], pa[b], pb[b]);
                    pb[b] = nr2[b] * pa[b]; pa[b] = na;
                }
        }
        float2 si[3];
        const float2* S2 = (const float2*)Sin;
#pragma unroll
        for (int b = 0; b < 3; ++b) si[b] = S2[(blk * 3 + b) * S_NO + s];
#pragma unroll
        for (int i = 0; i < 8; ++i) {
            float c = 0.0f;
#pragma unroll
            for (int b = 0; b < 3; ++b) {
                c = fmaf(pa[b], si[b].x, c);
                c = fmaf(pb[b], si[b].y, c);
                const float na = fmaf(tr[b], pa[b], pb[b]);
                pb[b] = nr2[b] * pa[b]; pa[b] = na;
            }
            filt[i] = Fws[(t0 + i) * S_NO + s] + c;
        }
    } else {
        // fallback: full 100-tap FIR (R5 rolling-window, proven)
        float acc[8] = {0,0,0,0,0,0,0,0};
        if (t0 >= J_PAD) {
            float w[15], kj[8];
            {
                const int B = t0 - 8;
#pragma unroll
                for (int q = 0; q < 15; ++q) w[q] = A[(B + q) * S_NO + s];
#pragma unroll
                for (int r = 0; r < 8; ++r) kj[r] = anc_kT[r * S_NO + s];
                k3_fma_chunk(w, kj, acc);
            }
#pragma unroll
            for (int c = 1; c < 13; ++c) {
                const int B = t0 - 8 * c - 8;
#pragma unroll
                for (int q = 6; q >= 0; --q) w[q + 8] = w[q];
#pragma unroll
                for (int q = 0; q < 8; ++q) w[q] = A[(B + q) * S_NO + s];
#pragma unroll
                for (int r = 0; r < 8; ++r) kj[r] = anc_kT[(8 * c + r) * S_NO + s];
                k3_fma_chunk(w, kj, acc);
            }
        } else {
            conv8_guard(A, anc_kT, t0, s, acc);
        }
#pragma unroll
        for (int i = 0; i < 8; ++i) filt[i] = acc[i];
    }

    if (fl == 0) {
        const float tsy = theta_syn[s], wsub = W_sub[s];
        const float wsp = W_spike[s],  tsp  = theta_spike[s];
#pragma unroll
        for (int i = 0; i < 8; ++i) {
            const int n = (t0 + i) * S_NO + s;
            const float x  = sigm(sc[i] + tsy + rr[i] + filt[i]);
            const float dn = fmaf(x, wsp, tsp);
            const float z  = sigm(dn + nz[i]);
            out0[n] = x * wsub;
            out1[n] = z;
            out2[n] = dn;
            out3[n] = dn;
        }
    } else {
#pragma unroll
        for (int i = 0; i < 8; ++i) Fws[(t0 + i) * S_NO + s] = filt[i];
    }
}

// ---------------------------------------------------------------------------
// K4: exact sequential recurrence (only when hist kernel != 0).
// ---------------------------------------------------------------------------
__global__ void __launch_bounds__(64) k4_scan(const float* __restrict__ S_conv,
                                              const float* __restrict__ noise,
                                              const float* __restrict__ W_sub,
                                              const float* __restrict__ theta_syn,
                                              const float* __restrict__ theta_spike,
                                              const float* __restrict__ W_spike,
                                              const float* __restrict__ hist_k,
                                              const int* __restrict__ flag,
                                              const float* __restrict__ Fws,
                                              float* __restrict__ out0,
                                              float* __restrict__ out1,
                                              float* __restrict__ out2,
                                              float* __restrict__ out3) {
    if (flag[0] == 0) return;
    __shared__ float zr[128];
    const int s = blockIdx.x;
    const int l = threadIdx.x;
    zr[l] = 0.0f; zr[l + 64] = 0.0f;      // single wave: no barrier needed
    const float hk0 = (l < T_HIST) ? hist_k[s * T_HIST + l] : 0.0f;
    const float hk1 = (l + 64 < T_HIST) ? hist_k[s * T_HIST + l + 64] : 0.0f;
    const float tsy = theta_syn[s], wsub = W_sub[s];
    const float wsp = W_spike[s],  tsp  = theta_spike[s];
    for (int t = 0; t < T_DATA; ++t) {
        float fh = hk0 * zr[(t - 1 - l) & 127];
        fh = fmaf(hk1, zr[(t - 65 - l) & 127], fh);
#pragma unroll
        for (int m = 1; m < 64; m <<= 1) fh += __shfl_xor(fh, m, 64);
        const int n = t * S_NO + s;
        const float basev = S_conv[n] + tsy + out1[n] + Fws[n];
        const float x  = sigm(basev + fh);
        const float dn = fmaf(x, wsp, tsp);
        const float z  = sigm(dn + noise[n]);
        if (l == 0) {
            out0[n] = x * wsub;
            out1[n] = z;
            out2[n] = dn;
            out3[n] = dn;
            zr[t & 127] = z;
        }
    }
}

// ---------------------------------------------------------------------------
extern "C" void kernel_launch(void* const* d_in, const int* in_sizes, int n_in,
                              void* d_out, int out_size, void* d_ws, size_t ws_size,
                              hipStream_t stream) {
    const float* S_conv  = (const float*)d_in[0];
    const float* Y_anc   = (const float*)d_in[1];
    const float* Z_anc   = (const float*)d_in[2];
    const float* noise   = (const float*)d_in[3];
    const float* C_den   = (const float*)d_in[4];
    const float* W_sub   = (const float*)d_in[5];
    const float* th_syn  = (const float*)d_in[6];
    const float* K_spk   = (const float*)d_in[7];
    const float* tau_spk = (const float*)d_in[8];
    const float* dl_spk  = (const float*)d_in[9];
    const float* th_spk  = (const float*)d_in[10];
    const float* W_spk   = (const float*)d_in[11];
    const float* tau_h   = (const float*)d_in[12];
    const float* K_h     = (const float*)d_in[13];
    const float* dl_h    = (const float*)d_in[14];

    float* out  = (float*)d_out;
    float* out0 = out;
    float* out1 = out + NELEM;
    float* out2 = out + 2 * NELEM;
    float* out3 = out + 3 * NELEM;

    // workspace: A | F | Ct | anc_kT | hist_k | flag[4] | cof | Ezs | Sin
    float* ws     = (float*)d_ws;
    float* wsA    = ws;
    float* wsF    = ws + NELEM;
    float* Ct     = ws + 2 * NELEM;
    float* anc_kT = Ct + S_NO * S_NO;
    float* hist_k = anc_kT + J_PAD * S_NO;
    int*   flag   = (int*)(hist_k + S_NO * T_HIST);
    float* cof    = (float*)(flag + 4);
    float* Ezs    = cof + 18 * S_NO;
    float* Sin    = Ezs + NTB * 3 * S_NO * 2;

    k1_prep<<<17, 256, 0, stream>>>(C_den, K_spk, tau_spk, dl_spk, tau_h, K_h, dl_h,
                                    Ct, anc_kT, hist_k, flag, cof);
    // A -> ws, R -> out1
    k2_gemm<<<T_DATA / 32, 256, 0, stream>>>(Z_anc, Y_anc, Ct, wsA, out1);
    // IIR conv: zero-state pass -> parallel state scan -> correction + final map
    k3a_iir<<<NTB / 2, 256, 0, stream>>>(wsA, tau_spk, cof, flag, wsF, Ezs);
    k3b_scan<<<384, 64, 0, stream>>>(tau_spk, flag, Ezs, Sin);
    k3c_final<<<K3_PHYS, 256, 0, stream>>>(wsA, anc_kT, tau_spk, Sin,
                                           S_conv, noise, W_sub, th_syn, th_spk,
                                           W_spk, flag, out0, out1, out2, out3, wsF);
    // exact sequential path (no-op when hist kernel is all-zero)
    k4_scan<<<S_NO, 64, 0, stream>>>(S_conv, noise, W_sub, th_syn, th_spk, W_spk,
                                     hist_k, flag, wsF, out0, out1, out2, out3);
}

// Round 8
// 161.825 us; speedup vs baseline: 1.6932x; 1.0937x over previous
//
#include <hip/hip_runtime.h>

#define T_DATA 20000
#define S_NO   128
#define T_HIST 100
#define J_PAD  104              // conv taps padded to 13 chunks of 8 (zeros past 99)
#define NELEM  (T_DATA * S_NO)  // 2,560,000

__device__ __forceinline__ float sigm(float v) {
    return 1.0f / (1.0f + __expf(-v));
}

__device__ __forceinline__ void fma4(float4& a, float s, const float4 c) {
    a.x = fmaf(s, c.x, a.x); a.y = fmaf(s, c.y, a.y);
    a.z = fmaf(s, c.z, a.z); a.w = fmaf(s, c.w, a.w);
}

// ---------------------------------------------------------------------------
// K1: prep (17 blocks). blocks 0..15: transpose C -> Ct[k][s]
// block 16: ancestor kernel transposed [j][s] (padded to 104), history
// kernel [s][j], flag = any(K_hist != 0)
// ---------------------------------------------------------------------------
__global__ void __launch_bounds__(256) k1_prep(const float* __restrict__ C,
                        const float* __restrict__ K_spike,
                        const float* __restrict__ tau_spike,
                        const float* __restrict__ delta_spike,
                        const float* __restrict__ tau_hist,
                        const float* __restrict__ K_hist,
                        const float* __restrict__ delta_hist,
                        float* __restrict__ Ct,
                        float* __restrict__ anc_kT,
                        float* __restrict__ hist_k,
                        int* __restrict__ flag) {
    const int tid = threadIdx.x;
    const int b   = blockIdx.x;
    if (b < 16) {
#pragma unroll
        for (int i = 0; i < 4; ++i) {
            const int q = b * 1024 + i * 256 + tid;   // q = s*128 + k
            Ct[(q & 127) * S_NO + (q >> 7)] = C[q];
        }
        return;
    }
    const int s    = tid & 127;
    const int half = tid >> 7;
    {   // ancestor kernel transposed, padded: anc_kT[j*128 + s], j in [0,104)
        float d  = delta_spike[s];
        float i0 = __expf(-tau_spike[0]);
        float i1 = __expf(-tau_spike[1]);
        float i2 = __expf(-tau_spike[2]);
        float k0 = K_spike[s * 3 + 0], k1 = K_spike[s * 3 + 1], k2 = K_spike[s * 3 + 2];
        for (int j = half * 52; j < half * 52 + 52; ++j) {
            float v = 0.0f;
            if (j < T_HIST) {
                float t  = fmaxf((float)j - d, 0.0f);
                float x0 = t * i0, x1 = t * i1, x2 = t * i2;
                v = k0 * x0 * __expf(-x0) + k1 * x1 * __expf(-x1) + k2 * x2 * __expf(-x2);
            }
            anc_kT[j * S_NO + s] = v;
        }
    }
    {   // history kernel per-subunit: hist_k[s*100 + j]
        float d  = delta_hist[s];
        float i0 = __expf(-tau_hist[0]);
        float i1 = __expf(-tau_hist[1]);
        float i2 = __expf(-tau_hist[2]);
        float k0 = K_hist[s * 3 + 0], k1 = K_hist[s * 3 + 1], k2 = K_hist[s * 3 + 2];
        for (int j = half * 50; j < half * 50 + 50; ++j) {
            float t  = fmaxf((float)j - d, 0.0f);
            float x0 = t * i0, x1 = t * i1, x2 = t * i2;
            hist_k[s * T_HIST + j] =
                k0 * x0 * __expf(-x0) + k1 * x1 * __expf(-x1) + k2 * x2 * __expf(-x2);
        }
    }
    if (tid == 0) *flag = 0;
    __syncthreads();
    if (tid < 128) {
        if (K_hist[s * 3] != 0.0f || K_hist[s * 3 + 1] != 0.0f || K_hist[s * 3 + 2] != 0.0f)
            atomicOr(flag, 1);
    }
}

// ---------------------------------------------------------------------------
// K2: dual GEMM  A = Z @ C^T (-> ws), R = Y @ C^T (-> out1)
// Known-good round-0 version: block 32t x 128s, thread 4t x 4s.
// ---------------------------------------------------------------------------
__global__ void __launch_bounds__(256) k2_gemm(const float* __restrict__ Z,
                                               const float* __restrict__ Y,
                                               const float* __restrict__ Ct,
                                               float* __restrict__ A,
                                               float* __restrict__ R) {
    __shared__ float Zt[32 * 128];
    __shared__ float Yt[32 * 128];
    const int t0  = blockIdx.x * 32;
    const int tid = threadIdx.x;
    {
        const float4* Zg = (const float4*)(Z + t0 * S_NO);
        const float4* Yg = (const float4*)(Y + t0 * S_NO);
        float4* Zl = (float4*)Zt;
        float4* Yl = (float4*)Yt;
        for (int q = tid; q < 1024; q += 256) { Zl[q] = Zg[q]; Yl[q] = Yg[q]; }
    }
    __syncthreads();
    const int sg = tid & 31;          // s0 = sg*4
    const int tg = tid >> 5;          // 0..7 -> local t = tg*4 + i
    const int s0 = sg * 4;
    float4 accA[4] = {{0,0,0,0},{0,0,0,0},{0,0,0,0},{0,0,0,0}};
    float4 accR[4] = {{0,0,0,0},{0,0,0,0},{0,0,0,0},{0,0,0,0}};
    for (int k4 = 0; k4 < 32; ++k4) {
        const float4 c0 = *(const float4*)&Ct[(k4 * 4 + 0) * S_NO + s0];
        const float4 c1 = *(const float4*)&Ct[(k4 * 4 + 1) * S_NO + s0];
        const float4 c2 = *(const float4*)&Ct[(k4 * 4 + 2) * S_NO + s0];
        const float4 c3 = *(const float4*)&Ct[(k4 * 4 + 3) * S_NO + s0];
#pragma unroll
        for (int i = 0; i < 4; ++i) {
            const float4 z = *(const float4*)&Zt[(tg * 4 + i) * S_NO + k4 * 4];
            fma4(accA[i], z.x, c0); fma4(accA[i], z.y, c1);
            fma4(accA[i], z.z, c2); fma4(accA[i], z.w, c3);
            const float4 y = *(const float4*)&Yt[(tg * 4 + i) * S_NO + k4 * 4];
            fma4(accR[i], y.x, c0); fma4(accR[i], y.y, c1);
            fma4(accR[i], y.z, c2); fma4(accR[i], y.w, c3);
        }
    }
#pragma unroll
    for (int i = 0; i < 4; ++i) {
        *(float4*)&A[(t0 + tg * 4 + i) * S_NO + s0] = accA[i];
        *(float4*)&R[(t0 + tg * 4 + i) * S_NO + s0] = accR[i];
    }
}

// ---------------------------------------------------------------------------
// K3: fused 100-tap conv + final map. Gather-from-global, no LDS/barrier.
// R5 best-measured version (162.5 us): 13-chunk loop fully unrolled with a
// rolling register window — adjacent chunks share 7 of 15 window rows, so
// chunks 1..12 load only 8 new rows each. Per-thread loads 299 -> 215.
// ---------------------------------------------------------------------------
#define K3_LOGICAL 1250
#define K3_NPER    157                 // ceil(1250/8)
#define K3_PHYS    (8 * K3_NPER)       // 1256

__device__ __forceinline__ void k3_fma_chunk(const float w[15], const float kj[8],
                                             float acc[8]) {
#pragma unroll
    for (int r = 0; r < 8; ++r)
#pragma unroll
        for (int i = 0; i < 8; ++i)
            acc[i] = fmaf(kj[r], w[i + 7 - r], acc[i]);   // row = t0+i-1-(8c+r)
}

// guarded (t0 < 104) fallback: serial, with u>=0 checks — 7 blocks only
__device__ __forceinline__ void conv8_guard(const float* __restrict__ A,
                                            const float* __restrict__ kT,
                                            int t0, int s, float acc[8]) {
#pragma unroll 1
    for (int c = 0; c < 13; ++c) {
        const int B = t0 - 8 * c - 8;
        float w[15], kj[8];
#pragma unroll
        for (int q = 0; q < 15; ++q) {
            const int u = B + q;
            w[q] = (u >= 0) ? A[u * S_NO + s] : 0.0f;
        }
#pragma unroll
        for (int r = 0; r < 8; ++r) kj[r] = kT[(8 * c + r) * S_NO + s];
        k3_fma_chunk(w, kj, acc);
    }
}

__global__ void __launch_bounds__(256, 4) k3_fused(const float* __restrict__ A,
                                                const float* __restrict__ anc_kT,
                                                const float* __restrict__ S_conv,
                                                const float* __restrict__ noise,
                                                const float* __restrict__ W_sub,
                                                const float* __restrict__ theta_syn,
                                                const float* __restrict__ theta_spike,
                                                const float* __restrict__ W_spike,
                                                const int* __restrict__ flag,
                                                float* __restrict__ out0,
                                                float* __restrict__ out1,
                                                float* __restrict__ out2,
                                                float* __restrict__ out3,
                                                float* __restrict__ Fws) {
    // bijective XCD swizzle over the padded grid [0, 1256)
    const int blk = (blockIdx.x & 7) * K3_NPER + (blockIdx.x >> 3);
    if (blk >= K3_LOGICAL) return;
    const int tid = threadIdx.x;
    const int s   = tid & 127;
    const int tg  = tid >> 7;                             // wave-uniform (0/1)
    const int t0  = blk * 16 + tg * 8;
    const int fl  = *flag;

    // prefetch the two HBM-cold final-map streams; latency hides under conv
    float sc[8], nz[8], rr[8];
#pragma unroll
    for (int i = 0; i < 8; ++i) {
        const int n = (t0 + i) * S_NO + s;
        sc[i] = S_conv[n];
        nz[i] = noise[n];
        rr[i] = out1[n];              // R = Y @ C^T, written by K2
    }

    float acc[8] = {0,0,0,0,0,0,0,0};
    if (t0 >= J_PAD) {
        float w[15], kj[8];
        {   // chunk 0: full 15-row window
            const int B = t0 - 8;
#pragma unroll
            for (int q = 0; q < 15; ++q) w[q] = A[(B + q) * S_NO + s];
#pragma unroll
            for (int r = 0; r < 8; ++r) kj[r] = anc_kT[r * S_NO + s];
            k3_fma_chunk(w, kj, acc);
        }
        // chunks 1..12: rolling window — shift 7 shared rows up (renamed at
        // compile time under full unroll), load only the 8 new rows.
#pragma unroll
        for (int c = 1; c < 13; ++c) {
            const int B = t0 - 8 * c - 8;
#pragma unroll
            for (int q = 6; q >= 0; --q) w[q + 8] = w[q];   // old rows B..B+6
#pragma unroll
            for (int q = 0; q < 8; ++q) w[q] = A[(B + q) * S_NO + s];
#pragma unroll
            for (int r = 0; r < 8; ++r) kj[r] = anc_kT[(8 * c + r) * S_NO + s];
            k3_fma_chunk(w, kj, acc);
        }
    } else {
        conv8_guard(A, anc_kT, t0, s, acc);
    }

    if (fl == 0) {
        const float tsy = theta_syn[s], wsub = W_sub[s];
        const float wsp = W_spike[s],  tsp  = theta_spike[s];
#pragma unroll
        for (int i = 0; i < 8; ++i) {
            const int n = (t0 + i) * S_NO + s;
            const float x  = sigm(sc[i] + tsy + rr[i] + acc[i]);
            const float dn = fmaf(x, wsp, tsp);
            const float z  = sigm(dn + nz[i]);
            out0[n] = x * wsub;
            out1[n] = z;
            out2[n] = dn;
            out3[n] = dn;
        }
    } else {
#pragma unroll
        for (int i = 0; i < 8; ++i) Fws[(t0 + i) * S_NO + s] = acc[i];
    }
}

// ---------------------------------------------------------------------------
// K4: exact sequential recurrence (only when hist kernel != 0).
// ---------------------------------------------------------------------------
__global__ void __launch_bounds__(64) k4_scan(const float* __restrict__ S_conv,
                                              const float* __restrict__ noise,
                                              const float* __restrict__ W_sub,
                                              const float* __restrict__ theta_syn,
                                              const float* __restrict__ theta_spike,
                                              const float* __restrict__ W_spike,
                                              const float* __restrict__ hist_k,
                                              const int* __restrict__ flag,
                                              const float* __restrict__ Fws,
                                              float* __restrict__ out0,
                                              float* __restrict__ out1,
                                              float* __restrict__ out2,
                                              float* __restrict__ out3) {
    if (*flag == 0) return;
    __shared__ float zr[128];
    const int s = blockIdx.x;
    const int l = threadIdx.x;
    zr[l] = 0.0f; zr[l + 64] = 0.0f;      // single wave: no barrier needed
    const float hk0 = (l < T_HIST) ? hist_k[s * T_HIST + l] : 0.0f;
    const float hk1 = (l + 64 < T_HIST) ? hist_k[s * T_HIST + l + 64] : 0.0f;
    const float tsy = theta_syn[s], wsub = W_sub[s];
    const float wsp = W_spike[s],  tsp  = theta_spike[s];
    for (int t = 0; t < T_DATA; ++t) {
        float fh = hk0 * zr[(t - 1 - l) & 127];
        fh = fmaf(hk1, zr[(t - 65 - l) & 127], fh);
#pragma unroll
        for (int m = 1; m < 64; m <<= 1) fh += __shfl_xor(fh, m, 64);
        const int n = t * S_NO + s;
        const float basev = S_conv[n] + tsy + out1[n] + Fws[n];
        const float x  = sigm(basev + fh);
        const float dn = fmaf(x, wsp, tsp);
        const float z  = sigm(dn + noise[n]);
        if (l == 0) {
            out0[n] = x * wsub;
            out1[n] = z;
            out2[n] = dn;
            out3[n] = dn;
            zr[t & 127] = z;
        }
    }
}

// ---------------------------------------------------------------------------
extern "C" void kernel_launch(void* const* d_in, const int* in_sizes, int n_in,
                              void* d_out, int out_size, void* d_ws, size_t ws_size,
                              hipStream_t stream) {
    const float* S_conv  = (const float*)d_in[0];
    const float* Y_anc   = (const float*)d_in[1];
    const float* Z_anc   = (const float*)d_in[2];
    const float* noise   = (const float*)d_in[3];
    const float* C_den   = (const float*)d_in[4];
    const float* W_sub   = (const float*)d_in[5];
    const float* th_syn  = (const float*)d_in[6];
    const float* K_spk   = (const float*)d_in[7];
    const float* tau_spk = (const float*)d_in[8];
    const float* dl_spk  = (const float*)d_in[9];
    const float* th_spk  = (const float*)d_in[10];
    const float* W_spk   = (const float*)d_in[11];
    const float* tau_h   = (const float*)d_in[12];
    const float* K_h     = (const float*)d_in[13];
    const float* dl_h    = (const float*)d_in[14];

    float* out  = (float*)d_out;
    float* out0 = out;
    float* out1 = out + NELEM;
    float* out2 = out + 2 * NELEM;
    float* out3 = out + 3 * NELEM;

    // workspace: A | F | Ct | anc_kT (104 rows) | hist_k | flag
    float* ws     = (float*)d_ws;
    float* wsA    = ws;
    float* wsF    = ws + NELEM;
    float* Ct     = ws + 2 * NELEM;
    float* anc_kT = Ct + S_NO * S_NO;
    float* hist_k = anc_kT + J_PAD * S_NO;
    int*   flag   = (int*)(hist_k + S_NO * T_HIST);

    k1_prep<<<17, 256, 0, stream>>>(C_den, K_spk, tau_spk, dl_spk, tau_h, K_h, dl_h,
                                    Ct, anc_kT, hist_k, flag);
    // A -> ws, R -> out1
    k2_gemm<<<T_DATA / 32, 256, 0, stream>>>(Z_anc, Y_anc, Ct, wsA, out1);
    // fused conv + final map (reads A from ws, R from out1)
    k3_fused<<<K3_PHYS, 256, 0, stream>>>(wsA, anc_kT, S_conv, noise,
                                          W_sub, th_syn, th_spk, W_spk,
                                          flag, out0, out1, out2, out3, wsF);
    // exact sequential path (no-op when hist kernel is all-zero)
    k4_scan<<<S_NO, 64, 0, stream>>>(S_conv, noise, W_sub, th_syn, th_spk, W_spk,
                                     hist_k, flag, wsF, out0, out1, out2, out3);
}